// Round 1
// 307.451 us; speedup vs baseline: 1.0492x; 1.0492x over previous
//
#include <hip/hip_runtime.h>
#include <stdint.h>

// GAT forward, MI355X. FP32 in/out; edge_index int32. N=50000, E=800000,
// HEADS=4, C=64 (HC=256).
// Pipeline (R9):
//   trans: Wfh/Wfl = trunc-split bf16 of W^T in MFMA-fragment-major order.
//   gemm:  H = x@W via split-bf16 MFMA (3 terms, err ~2^-17), H stored bf16.
//          64x256 block, X staged in padded LDS, B dbuf from L2.
//          R9: att logits a_src/a_dst computed in the gemm EPILOGUE from the
//          fp32 accumulators (wave w holds head w's 64 cols): 8 FMA + 8
//          shfl_xor per (mi,r). Removes att_kernel (51MB X re-read) and
//          prep_kernel entirely. Logit err ~1e-4 -> weight err ~2e-4 rel,
//          negligible vs bf16-H output error.
//   hist/scanA/scanC/scatter: CSR of edges grouped by destination.
//   gather: out = (w_self*h_i + sum_j w_j*h_j)/(sum w) + bias, PReLU.
//          R9: 16-edge batches. Lane (sub=lane&15) computes w for edge
//          k+sub of its head ONCE (was: all 16 lanes of a head group
//          redundantly exp'ing the same edge), broadcast via __shfl width
//          16. 16 H-rows in flight (was 8). csr_src over-read by <=15 ints
//          per tail batch (buffer padded +16, garbage j clamped, w=0).
// Softmax shift omitted: |e|<~12 -> exp<=1.6e5, fp32-safe; softmax is
// shift-invariant. Dominant output error = bf16 H storage (~0.016 absmax
// vs 0.0575 threshold, verified rounds 3/5/6/7).

using u16 = unsigned short;
typedef float f32x4 __attribute__((ext_vector_type(4)));
typedef __bf16 bf16x8 __attribute__((ext_vector_type(8)));
typedef u16 u16x8 __attribute__((ext_vector_type(8)));

#define NEG 0.2f
#define APAD 264   // 256 + 8 u16 pad: row stride 528 B -> 2-way LDS aliasing (free)

__device__ __forceinline__ float bf2f(u16 u) {
    union { uint32_t i; float f; } v; v.i = ((uint32_t)u) << 16; return v.f;
}
__device__ __forceinline__ u16 f2bf(float f) {          // RNE
    union { float f; uint32_t i; } v; v.f = f;
    uint32_t r = v.i + 0x7FFFu + ((v.i >> 16) & 1u);
    return (u16)(r >> 16);
}
// trunc split: f ~= hi + lo with |err| ~ 2^-17 |f|
__device__ __forceinline__ void split2(float f, u16& h, u16& l) {
    union { float f; uint32_t i; } v; v.f = f;
    h = (u16)(v.i >> 16);
    float r = f - bf2f(h);
    union { float f; uint32_t i; } w; w.f = r;
    l = (u16)(w.i >> 16);
}
__device__ __forceinline__ float wexp(float e) {
    e = e >= 0.f ? e : NEG * e;
    return __expf(e);
}

// ---------------- trans: fragment-major split W^T --------------------------
// Wf[((kg*16+nb)*64 + lane)*8 + j] = split(W[(kg*32+(lane>>4)*8+j)*256 + nb*16+(lane&15)])
__global__ __launch_bounds__(256) void trans_kernel(
    const float* __restrict__ W, u16* __restrict__ Wfh, u16* __restrict__ Wfl)
{
    const int f = blockIdx.x * 4 + (threadIdx.x >> 6);   // 128 frags = kg*16+nb
    const int l = threadIdx.x & 63;
    const int kg = f >> 4, nb = f & 15;
    const int n = nb * 16 + (l & 15);
    const int kb = kg * 32 + (l >> 4) * 8;
    u16x8 hv, lv;
#pragma unroll
    for (int j = 0; j < 8; j++) {
        u16 th, tl;
        split2(W[(size_t)(kb + j) * 256 + n], th, tl);
        hv[j] = th;
        lv[j] = tl;
    }
    *(u16x8*)(Wfh + ((size_t)f * 64 + l) * 8) = hv;
    *(u16x8*)(Wfl + ((size_t)f * 64 + l) * 8) = lv;
}

// ---------------- GEMM: H = x @ W, LDS-staged A, frag-major B --------------
// R9: att logits fused into the epilogue (wave w owns head w's columns).
__global__ __launch_bounds__(256, 2) void gemm_kernel(
    const float* __restrict__ X, const u16* __restrict__ Wfh,
    const u16* __restrict__ Wfl, const float* __restrict__ attS,
    const float* __restrict__ attD, u16* __restrict__ H,
    float* __restrict__ a_src, float* __restrict__ a_dst, int Nn)
{
    __shared__ u16 Ah[64 * APAD];
    __shared__ u16 Al[64 * APAD];
    const int tid = threadIdx.x, m0 = blockIdx.x * 64;
    const int wave = tid >> 6, lane = tid & 63;
    const int quad = lane >> 4, lr = lane & 15;

    // ---- stage X tile (64 rows x 256 cols) as split bf16 ----
#pragma unroll
    for (int i = 0; i < 16; i++) {
        const int f = i * 256 + tid;            // float4 index in tile
        const int row = f >> 6;                 // 64 float4 per row
        const int c4 = (f & 63) * 4;
        int grow = m0 + row;
        if (grow >= Nn) grow = Nn - 1;          // clamp; stores guarded
        const float4 v = *(const float4*)(X + (size_t)grow * 256 + c4);
        u16 h0, l0, h1, l1, h2, l2, h3, l3;
        split2(v.x, h0, l0); split2(v.y, h1, l1);
        split2(v.z, h2, l2); split2(v.w, h3, l3);
        uint2 hp, lp;
        hp.x = (uint32_t)h0 | ((uint32_t)h1 << 16);
        hp.y = (uint32_t)h2 | ((uint32_t)h3 << 16);
        lp.x = (uint32_t)l0 | ((uint32_t)l1 << 16);
        lp.y = (uint32_t)l2 | ((uint32_t)l3 << 16);
        *(uint2*)(Ah + row * APAD + c4) = hp;   // 8B aligned
        *(uint2*)(Al + row * APAD + c4) = lp;
    }
    __syncthreads();

    f32x4 acc[4][4] = {};                       // [mi][ni]
    bf16x8 bh[2][4], bl[2][4];                  // B double buffer

    // prologue: kg=0 B frags (frag id = kg*16 + wave*4 + ni)
#pragma unroll
    for (int ni = 0; ni < 4; ni++) {
        const size_t o = ((size_t)(wave * 4 + ni) * 64 + lane) * 8;
        bh[0][ni] = *(const bf16x8*)(Wfh + o);
        bl[0][ni] = *(const bf16x8*)(Wfl + o);
    }

#pragma unroll
    for (int kg = 0; kg < 8; kg++) {
        const int st = kg & 1, ns = st ^ 1;
        if (kg < 7) {                           // prefetch kg+1 B
#pragma unroll
            for (int ni = 0; ni < 4; ni++) {
                const size_t o = ((size_t)((kg + 1) * 16 + wave * 4 + ni) * 64 + lane) * 8;
                bh[ns][ni] = *(const bf16x8*)(Wfh + o);
                bl[ns][ni] = *(const bf16x8*)(Wfl + o);
            }
        }
        bf16x8 ah[4], al[4];
#pragma unroll
        for (int mi = 0; mi < 4; mi++) {
            const int o = (mi * 16 + lr) * APAD + kg * 32 + quad * 8;
            ah[mi] = *(const bf16x8*)(Ah + o);  // ds_read_b128
            al[mi] = *(const bf16x8*)(Al + o);
        }
#pragma unroll
        for (int ni = 0; ni < 4; ni++)
#pragma unroll
            for (int mi = 0; mi < 4; mi++) {
                acc[mi][ni] = __builtin_amdgcn_mfma_f32_16x16x32_bf16(
                    ah[mi], bh[st][ni], acc[mi][ni], 0, 0, 0);
                acc[mi][ni] = __builtin_amdgcn_mfma_f32_16x16x32_bf16(
                    ah[mi], bl[st][ni], acc[mi][ni], 0, 0, 0);
                acc[mi][ni] = __builtin_amdgcn_mfma_f32_16x16x32_bf16(
                    al[mi], bh[st][ni], acc[mi][ni], 0, 0, 0);
            }
    }

    // ---- epilogue 1: att logits from fp32 acc (wave = head) ----
    // a_src[row][wave] = sum_c acc(row, c) * attS[wave][c]; c = ni*16+lr.
    {
        float asv[4], adv[4];
#pragma unroll
        for (int ni = 0; ni < 4; ni++) {
            asv[ni] = attS[wave * 64 + ni * 16 + lr];
            adv[ni] = attD[wave * 64 + ni * 16 + lr];
        }
#pragma unroll
        for (int mi = 0; mi < 4; mi++)
#pragma unroll
            for (int r = 0; r < 4; r++) {
                float ps = 0.f, pd = 0.f;
#pragma unroll
                for (int ni = 0; ni < 4; ni++) {
                    ps += acc[mi][ni][r] * asv[ni];
                    pd += acc[mi][ni][r] * adv[ni];
                }
#pragma unroll
                for (int off = 8; off >= 1; off >>= 1) {
                    ps += __shfl_xor(ps, off, 16);   // reduce over lr group
                    pd += __shfl_xor(pd, off, 16);
                }
                if (lr == 0) {
                    const int row = m0 + mi * 16 + quad * 4 + r;
                    if (row < Nn) {
                        a_src[row * 4 + wave] = ps;
                        a_dst[row * 4 + wave] = pd;
                    }
                }
            }
    }

    // ---- epilogue 2: H store. C/D: col = lane&15 (lr), row = quad*4 + r ---
    const int n0 = wave * 64;
#pragma unroll
    for (int mi = 0; mi < 4; mi++)
#pragma unroll
        for (int ni = 0; ni < 4; ni++) {
            int col = n0 + ni * 16 + lr;
#pragma unroll
            for (int r = 0; r < 4; r++) {
                int row = m0 + mi * 16 + quad * 4 + r;
                if (row < Nn) H[(size_t)row * 256 + col] = f2bf(acc[mi][ni][r]);
            }
        }
}

// ---------------- CSR build ------------------------------------------------
__global__ void hist_kernel(const int* __restrict__ dst, int* __restrict__ deg,
                            int E, int Nn)
{
    for (int e = blockIdx.x * blockDim.x + threadIdx.x; e < E;
         e += gridDim.x * blockDim.x) {
        int i = dst[e];
        i = ((unsigned)i < (unsigned)Nn) ? i : 0;
        atomicAdd(&deg[i], 1);
    }
}

__global__ __launch_bounds__(1024) void scanA_kernel(
    const int* __restrict__ deg, int* __restrict__ offs,
    int* __restrict__ bsum, int Nn)
{
    __shared__ int wsum[16];
    const int t = threadIdx.x, wv = t >> 6, ln = t & 63;
    const int idx = blockIdx.x * 1024 + t;
    int v = (idx < Nn) ? deg[idx] : 0;
    int s = v;
#pragma unroll
    for (int o = 1; o < 64; o <<= 1) {
        int u = __shfl_up(s, o, 64);
        if (ln >= o) s += u;
    }
    if (ln == 63) wsum[wv] = s;
    __syncthreads();
    if (t == 0) {
        int run = 0;
#pragma unroll
        for (int w = 0; w < 16; w++) { int x = wsum[w]; wsum[w] = run; run += x; }
        bsum[blockIdx.x] = run;
    }
    __syncthreads();
    if (idx < Nn) offs[idx] = wsum[wv] + s - v;      // block-local exclusive
}

// scanC: adds spine prefix (computed in-block from raw bsum) — scanB folded in.
__global__ __launch_bounds__(1024) void scanC_kernel(
    int* __restrict__ offs, const int* __restrict__ bsum,
    int* __restrict__ cur, int Nn, int nb)
{
    __shared__ int prefix;
    if (threadIdx.x == 0) prefix = 0;
    __syncthreads();
    if (threadIdx.x < 64) {
        const int t = threadIdx.x;
        int v = (t < nb) ? bsum[t] : 0;
        int s = v;
#pragma unroll
        for (int o = 1; o < 64; o <<= 1) {
            int u = __shfl_up(s, o, 64);
            if (t >= o) s += u;
        }
        if ((int)blockIdx.x > 0 && t == (int)blockIdx.x - 1) prefix = s;
    }
    __syncthreads();
    const int idx = blockIdx.x * 1024 + threadIdx.x;
    if (idx < Nn) {
        int o = offs[idx] + prefix;
        offs[idx] = o;
        cur[idx] = o;
    }
}

__global__ void scatter_kernel(
    const int* __restrict__ src, const int* __restrict__ dst,
    int* __restrict__ cur, int* __restrict__ csr_src, int E, int Nn)
{
    for (int e = blockIdx.x * blockDim.x + threadIdx.x; e < E;
         e += gridDim.x * blockDim.x) {
        int j = src[e], i = dst[e];
        j = ((unsigned)j < (unsigned)Nn) ? j : 0;
        i = ((unsigned)i < (unsigned)Nn) ? i : 0;
        int pos = atomicAdd(&cur[i], 1);
        if ((unsigned)pos < (unsigned)E) csr_src[pos] = j;
    }
}

// ---------------- gather: 1 wave/node, 4 ch/thread, 16-edge batches --------
// Lane sub (=lane&15) computes w for edge k+sub of head (lane>>4) once;
// broadcast via __shfl width 16. 16 H rows in flight. Tail batches clamp
// the w-lane index and zero w; H-row index for dead slots comes straight
// from csr_src (over-read <=15 ints into the +16 pad), clamped to [0,Nn).
__global__ __launch_bounds__(256) void gather_kernel(
    const u16* __restrict__ H, const int* __restrict__ offs,
    const int* __restrict__ deg, const int* __restrict__ csr_src,
    const float* __restrict__ a_src, const float* __restrict__ a_dst,
    const float* __restrict__ bias, const float* __restrict__ prelu,
    float* __restrict__ out, int Nn)
{
    const int wave = threadIdx.x >> 6, lane = threadIdx.x & 63;
    const int node = blockIdx.x * 4 + wave;
    if (node >= Nn) return;
    const int head = lane >> 4;
    const int sub  = lane & 15;
    const int c = lane * 4;                          // 4 channels / thread

    const float adv = a_dst[node * 4 + head];
    float acc0, acc1, acc2, acc3, sumw;
    {   // self loop
        float ws = wexp(a_src[node * 4 + head] + adv);
        uint2 hv = *(const uint2*)(H + (size_t)node * 256 + c);
        acc0 = ws * bf2f((u16)hv.x);
        acc1 = ws * bf2f((u16)(hv.x >> 16));
        acc2 = ws * bf2f((u16)hv.y);
        acc3 = ws * bf2f((u16)(hv.y >> 16));
        sumw = ws;
    }
    const int d = deg[node];
    const int* __restrict__ cp = csr_src + offs[node];

    for (int k = 0; k < d; k += 16) {
        const int q = d - k;                         // edges left (>=1)
        // phase A: one lane per (edge, head) computes the weight
        const int es = (sub < q) ? sub : q - 1;
        const int jj = cp[k + es];
        float ww = wexp(a_src[jj * 4 + head] + adv);
        ww = (sub < q) ? ww : 0.f;
        // phase B: 16 H-rows in flight
        uint2 hv[16];
#pragma unroll
        for (int t = 0; t < 16; t++) {
            int jt = cp[k + t];                      // may over-read into pad
            jt = ((unsigned)jt < (unsigned)Nn) ? jt : 0;
            hv[t] = *(const uint2*)(H + ((size_t)jt << 8) + c);
        }
#pragma unroll
        for (int t = 0; t < 16; t++) {
            const float w = __shfl(ww, t, 16);       // broadcast in head group
            acc0 += w * bf2f((u16)hv[t].x);
            acc1 += w * bf2f((u16)(hv[t].x >> 16));
            acc2 += w * bf2f((u16)hv[t].y);
            acc3 += w * bf2f((u16)(hv[t].y >> 16));
            sumw += w;
        }
    }

    const float inv = 1.f / (sumw + 1e-16f);
    const float pa = prelu[0];
    const float4 bv = *(const float4*)(bias + c);
    float4 ov;
    ov.x = acc0 * inv + bv.x; ov.x = ov.x >= 0.f ? ov.x : pa * ov.x;
    ov.y = acc1 * inv + bv.y; ov.y = ov.y >= 0.f ? ov.y : pa * ov.y;
    ov.z = acc2 * inv + bv.z; ov.z = ov.z >= 0.f ? ov.z : pa * ov.z;
    ov.w = acc3 * inv + bv.w; ov.w = ov.w >= 0.f ? ov.w : pa * ov.w;
    *(float4*)(out + (size_t)node * 256 + c) = ov;
}

// ---------------------------------------------------------------------------
extern "C" void kernel_launch(void* const* d_in, const int* in_sizes, int n_in,
                              void* d_out, int out_size, void* d_ws, size_t ws_size,
                              hipStream_t stream)
{
    const float* X    = (const float*)d_in[0];
    const int*   EI   = (const int*)d_in[1];
    const float* W    = (const float*)d_in[2];
    const float* attS = (const float*)d_in[3];
    const float* attD = (const float*)d_in[4];
    const float* bias = (const float*)d_in[5];
    const float* pa   = (const float*)d_in[6];

    const int Nn = in_sizes[0] / 256;   // 50000
    const int E  = in_sizes[1] / 2;     // 800000
    const int* esrc = EI;
    const int* edst = EI + E;
    const int nbScan = (Nn + 1023) / 1024;   // 49 <= 64

    // workspace carve (~31 MB), all segments 16B-aligned
    char* p = (char*)d_ws;
    u16*   H       = (u16*)p;   p += (size_t)Nn * 256 * 2;
    float* a_src   = (float*)p; p += (size_t)Nn * 4 * 4;
    float* a_dst   = (float*)p; p += (size_t)Nn * 4 * 4;
    u16*   Wfh     = (u16*)p;   p += 256 * 256 * 2;
    u16*   Wfl     = (u16*)p;   p += 256 * 256 * 2;
    int*   deg     = (int*)p;   p += (size_t)Nn * 4;
    int*   offs    = (int*)p;   p += (size_t)Nn * 4;
    int*   cur     = (int*)p;   p += (size_t)Nn * 4;
    int*   bsum    = (int*)p;   p += 64 * 4;
    int*   csr_src = (int*)p;   p += ((size_t)E + 16) * 4;  // +16 pad: gather over-read

    (void)hipMemsetAsync(deg, 0, (size_t)Nn * 4, stream);

    trans_kernel<<<32, 256, 0, stream>>>(W, Wfh, Wfl);
    gemm_kernel<<<(Nn + 63) / 64, 256, 0, stream>>>(X, Wfh, Wfl, attS, attD,
                                                    H, a_src, a_dst, Nn);
    hist_kernel<<<2048, 256, 0, stream>>>(edst, deg, E, Nn);
    scanA_kernel<<<nbScan, 1024, 0, stream>>>(deg, offs, bsum, Nn);
    scanC_kernel<<<nbScan, 1024, 0, stream>>>(offs, bsum, cur, Nn, nbScan);
    scatter_kernel<<<2048, 256, 0, stream>>>(esrc, edst, cur, csr_src, E, Nn);
    gather_kernel<<<(Nn + 3) / 4, 256, 0, stream>>>(H, offs, deg, csr_src,
                                                    a_src, a_dst, bias, pa,
                                                    (float*)d_out, Nn);
}

// Round 2
// 297.285 us; speedup vs baseline: 1.0851x; 1.0342x over previous
//
#include <hip/hip_runtime.h>
#include <stdint.h>

// GAT forward, MI355X. FP32 in/out; edge_index int32. N=50000, E=800000,
// HEADS=4, C=64 (HC=256).
// Pipeline (R10):
//   trans: Wfh/Wfl = trunc-split bf16 of W^T in MFMA-fragment-major order.
//   gemm:  H = x@W via split-bf16 MFMA (3 terms, err ~2^-17), H stored bf16.
//          64x256 block, X staged in padded LDS, B dbuf from L2.
//          att logits a_src/a_dst computed in the gemm EPILOGUE from the
//          fp32 accumulators (wave w holds head w's 64 cols).
//   hist/scanA/scanC/scatter: CSR of edges grouped by destination.
//   gather: out = (w_self*h_i + sum_j w_j*h_j)/(sum w) + bias, PReLU.
//          R10: 16-edge batches, lane sub=lane&15 loads edge id jj ONCE
//          (index clamped to q-1 in tails) and computes w for its head once;
//          both j and w are broadcast via __shfl width 16. Dead tail slots
//          therefore re-read the LAST VALID edge's H row (L1/L2-hot) instead
//          of the next node's edges — R9's +22MB dead-fetch regression
//          (FETCH 211->233MB, dur 69->83us) is removed, and 16 broadcast
//          cp[] loads/batch become shuffles.
// Softmax shift omitted: logits fp32-exact-ish (err ~1e-4), |e|<~12 ->
// exp<=1.6e5, fp32-safe; softmax is shift-invariant. Dominant output error =
// bf16 H storage (~0.016 absmax vs 0.0575 threshold, verified rounds 3-9).

using u16 = unsigned short;
typedef float f32x4 __attribute__((ext_vector_type(4)));
typedef __bf16 bf16x8 __attribute__((ext_vector_type(8)));
typedef u16 u16x8 __attribute__((ext_vector_type(8)));

#define NEG 0.2f
#define APAD 264   // 256 + 8 u16 pad: row stride 528 B -> 2-way LDS aliasing (free)

__device__ __forceinline__ float bf2f(u16 u) {
    union { uint32_t i; float f; } v; v.i = ((uint32_t)u) << 16; return v.f;
}
__device__ __forceinline__ u16 f2bf(float f) {          // RNE
    union { float f; uint32_t i; } v; v.f = f;
    uint32_t r = v.i + 0x7FFFu + ((v.i >> 16) & 1u);
    return (u16)(r >> 16);
}
// trunc split: f ~= hi + lo with |err| ~ 2^-17 |f|
__device__ __forceinline__ void split2(float f, u16& h, u16& l) {
    union { float f; uint32_t i; } v; v.f = f;
    h = (u16)(v.i >> 16);
    float r = f - bf2f(h);
    union { float f; uint32_t i; } w; w.f = r;
    l = (u16)(w.i >> 16);
}
__device__ __forceinline__ float wexp(float e) {
    e = e >= 0.f ? e : NEG * e;
    return __expf(e);
}

// ---------------- trans: fragment-major split W^T --------------------------
// Wf[((kg*16+nb)*64 + lane)*8 + j] = split(W[(kg*32+(lane>>4)*8+j)*256 + nb*16+(lane&15)])
__global__ __launch_bounds__(256) void trans_kernel(
    const float* __restrict__ W, u16* __restrict__ Wfh, u16* __restrict__ Wfl)
{
    const int f = blockIdx.x * 4 + (threadIdx.x >> 6);   // 128 frags = kg*16+nb
    const int l = threadIdx.x & 63;
    const int kg = f >> 4, nb = f & 15;
    const int n = nb * 16 + (l & 15);
    const int kb = kg * 32 + (l >> 4) * 8;
    u16x8 hv, lv;
#pragma unroll
    for (int j = 0; j < 8; j++) {
        u16 th, tl;
        split2(W[(size_t)(kb + j) * 256 + n], th, tl);
        hv[j] = th;
        lv[j] = tl;
    }
    *(u16x8*)(Wfh + ((size_t)f * 64 + l) * 8) = hv;
    *(u16x8*)(Wfl + ((size_t)f * 64 + l) * 8) = lv;
}

// ---------------- GEMM: H = x @ W, LDS-staged A, frag-major B --------------
// att logits fused into the epilogue (wave w owns head w's columns).
__global__ __launch_bounds__(256, 2) void gemm_kernel(
    const float* __restrict__ X, const u16* __restrict__ Wfh,
    const u16* __restrict__ Wfl, const float* __restrict__ attS,
    const float* __restrict__ attD, u16* __restrict__ H,
    float* __restrict__ a_src, float* __restrict__ a_dst, int Nn)
{
    __shared__ u16 Ah[64 * APAD];
    __shared__ u16 Al[64 * APAD];
    const int tid = threadIdx.x, m0 = blockIdx.x * 64;
    const int wave = tid >> 6, lane = tid & 63;
    const int quad = lane >> 4, lr = lane & 15;

    // ---- stage X tile (64 rows x 256 cols) as split bf16 ----
#pragma unroll
    for (int i = 0; i < 16; i++) {
        const int f = i * 256 + tid;            // float4 index in tile
        const int row = f >> 6;                 // 64 float4 per row
        const int c4 = (f & 63) * 4;
        int grow = m0 + row;
        if (grow >= Nn) grow = Nn - 1;          // clamp; stores guarded
        const float4 v = *(const float4*)(X + (size_t)grow * 256 + c4);
        u16 h0, l0, h1, l1, h2, l2, h3, l3;
        split2(v.x, h0, l0); split2(v.y, h1, l1);
        split2(v.z, h2, l2); split2(v.w, h3, l3);
        uint2 hp, lp;
        hp.x = (uint32_t)h0 | ((uint32_t)h1 << 16);
        hp.y = (uint32_t)h2 | ((uint32_t)h3 << 16);
        lp.x = (uint32_t)l0 | ((uint32_t)l1 << 16);
        lp.y = (uint32_t)l2 | ((uint32_t)l3 << 16);
        *(uint2*)(Ah + row * APAD + c4) = hp;   // 8B aligned
        *(uint2*)(Al + row * APAD + c4) = lp;
    }
    __syncthreads();

    f32x4 acc[4][4] = {};                       // [mi][ni]
    bf16x8 bh[2][4], bl[2][4];                  // B double buffer

    // prologue: kg=0 B frags (frag id = kg*16 + wave*4 + ni)
#pragma unroll
    for (int ni = 0; ni < 4; ni++) {
        const size_t o = ((size_t)(wave * 4 + ni) * 64 + lane) * 8;
        bh[0][ni] = *(const bf16x8*)(Wfh + o);
        bl[0][ni] = *(const bf16x8*)(Wfl + o);
    }

#pragma unroll
    for (int kg = 0; kg < 8; kg++) {
        const int st = kg & 1, ns = st ^ 1;
        if (kg < 7) {                           // prefetch kg+1 B
#pragma unroll
            for (int ni = 0; ni < 4; ni++) {
                const size_t o = ((size_t)((kg + 1) * 16 + wave * 4 + ni) * 64 + lane) * 8;
                bh[ns][ni] = *(const bf16x8*)(Wfh + o);
                bl[ns][ni] = *(const bf16x8*)(Wfl + o);
            }
        }
        bf16x8 ah[4], al[4];
#pragma unroll
        for (int mi = 0; mi < 4; mi++) {
            const int o = (mi * 16 + lr) * APAD + kg * 32 + quad * 8;
            ah[mi] = *(const bf16x8*)(Ah + o);  // ds_read_b128
            al[mi] = *(const bf16x8*)(Al + o);
        }
#pragma unroll
        for (int ni = 0; ni < 4; ni++)
#pragma unroll
            for (int mi = 0; mi < 4; mi++) {
                acc[mi][ni] = __builtin_amdgcn_mfma_f32_16x16x32_bf16(
                    ah[mi], bh[st][ni], acc[mi][ni], 0, 0, 0);
                acc[mi][ni] = __builtin_amdgcn_mfma_f32_16x16x32_bf16(
                    ah[mi], bl[st][ni], acc[mi][ni], 0, 0, 0);
                acc[mi][ni] = __builtin_amdgcn_mfma_f32_16x16x32_bf16(
                    al[mi], bh[st][ni], acc[mi][ni], 0, 0, 0);
            }
    }

    // ---- epilogue 1: att logits from fp32 acc (wave = head) ----
    // a_src[row][wave] = sum_c acc(row, c) * attS[wave][c]; c = ni*16+lr.
    {
        float asv[4], adv[4];
#pragma unroll
        for (int ni = 0; ni < 4; ni++) {
            asv[ni] = attS[wave * 64 + ni * 16 + lr];
            adv[ni] = attD[wave * 64 + ni * 16 + lr];
        }
#pragma unroll
        for (int mi = 0; mi < 4; mi++)
#pragma unroll
            for (int r = 0; r < 4; r++) {
                float ps = 0.f, pd = 0.f;
#pragma unroll
                for (int ni = 0; ni < 4; ni++) {
                    ps += acc[mi][ni][r] * asv[ni];
                    pd += acc[mi][ni][r] * adv[ni];
                }
#pragma unroll
                for (int off = 8; off >= 1; off >>= 1) {
                    ps += __shfl_xor(ps, off, 16);   // reduce over lr group
                    pd += __shfl_xor(pd, off, 16);
                }
                if (lr == 0) {
                    const int row = m0 + mi * 16 + quad * 4 + r;
                    if (row < Nn) {
                        a_src[row * 4 + wave] = ps;
                        a_dst[row * 4 + wave] = pd;
                    }
                }
            }
    }

    // ---- epilogue 2: H store. C/D: col = lane&15 (lr), row = quad*4 + r ---
    const int n0 = wave * 64;
#pragma unroll
    for (int mi = 0; mi < 4; mi++)
#pragma unroll
        for (int ni = 0; ni < 4; ni++) {
            int col = n0 + ni * 16 + lr;
#pragma unroll
            for (int r = 0; r < 4; r++) {
                int row = m0 + mi * 16 + quad * 4 + r;
                if (row < Nn) H[(size_t)row * 256 + col] = f2bf(acc[mi][ni][r]);
            }
        }
}

// ---------------- CSR build ------------------------------------------------
__global__ void hist_kernel(const int* __restrict__ dst, int* __restrict__ deg,
                            int E, int Nn)
{
    for (int e = blockIdx.x * blockDim.x + threadIdx.x; e < E;
         e += gridDim.x * blockDim.x) {
        int i = dst[e];
        i = ((unsigned)i < (unsigned)Nn) ? i : 0;
        atomicAdd(&deg[i], 1);
    }
}

__global__ __launch_bounds__(1024) void scanA_kernel(
    const int* __restrict__ deg, int* __restrict__ offs,
    int* __restrict__ bsum, int Nn)
{
    __shared__ int wsum[16];
    const int t = threadIdx.x, wv = t >> 6, ln = t & 63;
    const int idx = blockIdx.x * 1024 + t;
    int v = (idx < Nn) ? deg[idx] : 0;
    int s = v;
#pragma unroll
    for (int o = 1; o < 64; o <<= 1) {
        int u = __shfl_up(s, o, 64);
        if (ln >= o) s += u;
    }
    if (ln == 63) wsum[wv] = s;
    __syncthreads();
    if (t == 0) {
        int run = 0;
#pragma unroll
        for (int w = 0; w < 16; w++) { int x = wsum[w]; wsum[w] = run; run += x; }
        bsum[blockIdx.x] = run;
    }
    __syncthreads();
    if (idx < Nn) offs[idx] = wsum[wv] + s - v;      // block-local exclusive
}

// scanC: adds spine prefix (computed in-block from raw bsum) — scanB folded in.
__global__ __launch_bounds__(1024) void scanC_kernel(
    int* __restrict__ offs, const int* __restrict__ bsum,
    int* __restrict__ cur, int Nn, int nb)
{
    __shared__ int prefix;
    if (threadIdx.x == 0) prefix = 0;
    __syncthreads();
    if (threadIdx.x < 64) {
        const int t = threadIdx.x;
        int v = (t < nb) ? bsum[t] : 0;
        int s = v;
#pragma unroll
        for (int o = 1; o < 64; o <<= 1) {
            int u = __shfl_up(s, o, 64);
            if (t >= o) s += u;
        }
        if ((int)blockIdx.x > 0 && t == (int)blockIdx.x - 1) prefix = s;
    }
    __syncthreads();
    const int idx = blockIdx.x * 1024 + threadIdx.x;
    if (idx < Nn) {
        int o = offs[idx] + prefix;
        offs[idx] = o;
        cur[idx] = o;
    }
}

__global__ void scatter_kernel(
    const int* __restrict__ src, const int* __restrict__ dst,
    int* __restrict__ cur, int* __restrict__ csr_src, int E, int Nn)
{
    for (int e = blockIdx.x * blockDim.x + threadIdx.x; e < E;
         e += gridDim.x * blockDim.x) {
        int j = src[e], i = dst[e];
        j = ((unsigned)j < (unsigned)Nn) ? j : 0;
        i = ((unsigned)i < (unsigned)Nn) ? i : 0;
        int pos = atomicAdd(&cur[i], 1);
        if ((unsigned)pos < (unsigned)E) csr_src[pos] = j;
    }
}

// ---------------- gather: 1 wave/node, 4 ch/thread, 16-edge batches --------
// Lane sub (=lane&15) loads edge id jj = cp[k+min(sub,q-1)] (always in-range)
// and computes w for head (lane>>4) once. Row ids AND weights broadcast via
// __shfl width 16: dead tail slots re-read the last valid edge's H row
// (cache-hot, w=0) instead of touching neighbor nodes' edges. 16 H rows in
// flight; no csr over-read at all.
__global__ __launch_bounds__(256) void gather_kernel(
    const u16* __restrict__ H, const int* __restrict__ offs,
    const int* __restrict__ deg, const int* __restrict__ csr_src,
    const float* __restrict__ a_src, const float* __restrict__ a_dst,
    const float* __restrict__ bias, const float* __restrict__ prelu,
    float* __restrict__ out, int Nn)
{
    const int wave = threadIdx.x >> 6, lane = threadIdx.x & 63;
    const int node = blockIdx.x * 4 + wave;
    if (node >= Nn) return;
    const int head = lane >> 4;
    const int sub  = lane & 15;
    const int c = lane * 4;                          // 4 channels / thread

    const float adv = a_dst[node * 4 + head];
    float acc0, acc1, acc2, acc3, sumw;
    {   // self loop
        float ws = wexp(a_src[node * 4 + head] + adv);
        uint2 hv = *(const uint2*)(H + (size_t)node * 256 + c);
        acc0 = ws * bf2f((u16)hv.x);
        acc1 = ws * bf2f((u16)(hv.x >> 16));
        acc2 = ws * bf2f((u16)hv.y);
        acc3 = ws * bf2f((u16)(hv.y >> 16));
        sumw = ws;
    }
    const int d = deg[node];
    const int* __restrict__ cp = csr_src + offs[node];

    for (int k = 0; k < d; k += 16) {
        const int q = d - k;                         // edges left (>=1)
        // phase A: lane sub owns edge k+sub (clamped): 1 edge-id load,
        // 1 a_src load, 1 exp — per (edge, head).
        const int es = (sub < q) ? sub : q - 1;
        const int jj = cp[k + es];                   // in-range always
        float ww = wexp(a_src[jj * 4 + head] + adv);
        ww = (sub < q) ? ww : 0.f;
        // phase B: 16 H-rows in flight; row id via shuffle (clamped ids ->
        // dead slots hit the same line as the last valid edge).
        uint2 hv[16];
#pragma unroll
        for (int t = 0; t < 16; t++) {
            const int jt = __shfl(jj, t, 16);        // broadcast in head group
            hv[t] = *(const uint2*)(H + ((size_t)jt << 8) + c);
        }
#pragma unroll
        for (int t = 0; t < 16; t++) {
            const float w = __shfl(ww, t, 16);       // broadcast in head group
            acc0 += w * bf2f((u16)hv[t].x);
            acc1 += w * bf2f((u16)(hv[t].x >> 16));
            acc2 += w * bf2f((u16)hv[t].y);
            acc3 += w * bf2f((u16)(hv[t].y >> 16));
            sumw += w;
        }
    }

    const float inv = 1.f / (sumw + 1e-16f);
    const float pa = prelu[0];
    const float4 bv = *(const float4*)(bias + c);
    float4 ov;
    ov.x = acc0 * inv + bv.x; ov.x = ov.x >= 0.f ? ov.x : pa * ov.x;
    ov.y = acc1 * inv + bv.y; ov.y = ov.y >= 0.f ? ov.y : pa * ov.y;
    ov.z = acc2 * inv + bv.z; ov.z = ov.z >= 0.f ? ov.z : pa * ov.z;
    ov.w = acc3 * inv + bv.w; ov.w = ov.w >= 0.f ? ov.w : pa * ov.w;
    *(float4*)(out + (size_t)node * 256 + c) = ov;
}

// ---------------------------------------------------------------------------
extern "C" void kernel_launch(void* const* d_in, const int* in_sizes, int n_in,
                              void* d_out, int out_size, void* d_ws, size_t ws_size,
                              hipStream_t stream)
{
    const float* X    = (const float*)d_in[0];
    const int*   EI   = (const int*)d_in[1];
    const float* W    = (const float*)d_in[2];
    const float* attS = (const float*)d_in[3];
    const float* attD = (const float*)d_in[4];
    const float* bias = (const float*)d_in[5];
    const float* pa   = (const float*)d_in[6];

    const int Nn = in_sizes[0] / 256;   // 50000
    const int E  = in_sizes[1] / 2;     // 800000
    const int* esrc = EI;
    const int* edst = EI + E;
    const int nbScan = (Nn + 1023) / 1024;   // 49 <= 64

    // workspace carve (~31 MB), all segments 16B-aligned
    char* p = (char*)d_ws;
    u16*   H       = (u16*)p;   p += (size_t)Nn * 256 * 2;
    float* a_src   = (float*)p; p += (size_t)Nn * 4 * 4;
    float* a_dst   = (float*)p; p += (size_t)Nn * 4 * 4;
    u16*   Wfh     = (u16*)p;   p += 256 * 256 * 2;
    u16*   Wfl     = (u16*)p;   p += 256 * 256 * 2;
    int*   deg     = (int*)p;   p += (size_t)Nn * 4;
    int*   offs    = (int*)p;   p += (size_t)Nn * 4;
    int*   cur     = (int*)p;   p += (size_t)Nn * 4;
    int*   bsum    = (int*)p;   p += 64 * 4;
    int*   csr_src = (int*)p;   p += ((size_t)E + 16) * 4;  // +16 pad (unused now, harmless)

    (void)hipMemsetAsync(deg, 0, (size_t)Nn * 4, stream);

    trans_kernel<<<32, 256, 0, stream>>>(W, Wfh, Wfl);
    gemm_kernel<<<(Nn + 63) / 64, 256, 0, stream>>>(X, Wfh, Wfl, attS, attD,
                                                    H, a_src, a_dst, Nn);
    hist_kernel<<<2048, 256, 0, stream>>>(edst, deg, E, Nn);
    scanA_kernel<<<nbScan, 1024, 0, stream>>>(deg, offs, bsum, Nn);
    scanC_kernel<<<nbScan, 1024, 0, stream>>>(offs, bsum, cur, Nn, nbScan);
    scatter_kernel<<<2048, 256, 0, stream>>>(esrc, edst, cur, csr_src, E, Nn);
    gather_kernel<<<(Nn + 3) / 4, 256, 0, stream>>>(H, offs, deg, csr_src,
                                                    a_src, a_dst, bias, pa,
                                                    (float*)d_out, Nn);
}